// Round 3
// baseline (56.545 us; speedup 1.0000x reference)
//
#include <hip/hip_runtime.h>
#include <hip/hip_bf16.h>

// Flow_6081673691683: Heun flow (10 steps x 2 MLP evals, H=256) + analytic logdet.
// Key insight: per-step Jacobian det == P^24 exactly (two unit shears + mixing),
// so logabsdet = 240*ln(0.95) is a constant -> jacrev/slogdet eliminated.

typedef unsigned short ushort_t;
typedef float f32x4 __attribute__((ext_vector_type(4)));
typedef short s16x8 __attribute__((ext_vector_type(8)));
typedef int   i32x4 __attribute__((ext_vector_type(4)));

#define NB      2048
#define OBS_D   48
#define HDIM    256
#define ADIM    12
#define XDIM    24
#define NSTEPS  10
#define DT      0.1f
#define PP      0.95f

// d_ws layout (ushort / bf16 elements)
#define W1U 0        // 2kt * 16nt * 64 * 8 = 16384
#define W2U 16384    // 8kt * 16nt * 64 * 8 = 65536
#define W3U 81920    // 65536
#define W4U 147456   // 8kt * 1nt * 64 * 8 = 4096
#define N_FRAG 151552
#define FRAG_BLOCKS 592   // 592*256 == 151552
#define LP_BLOCKS 8       // 8*256 == 2048

// LDS layout (bytes)
#define LDS_W2   0        // 131072
#define LDS_BUFA 131072   // 8192  (16 rows x 256 bf16, swizzled)
#define LDS_BUFB 139264   // 8192  (also L4 partial buffer: 8 waves x 256 f32)
#define LDS_AIN  147456   // 2048  (16 rows x 64 bf16: [act12|obs48|t|1|0|0], swizzled)
#define LDS_Z    149504   // 1024  (16x16 f32, cols<12 valid)
#define LDS_Y    150528   // 1024
#define LDS_ZI   151552   // 1024
#define LDS_TOTAL 152576

__device__ __forceinline__ ushort_t f2bf(float f) {
  unsigned u = __builtin_bit_cast(unsigned, f);
  u += 0x7fffu + ((u >> 16) & 1u);          // RNE
  return (ushort_t)(u >> 16);
}

__device__ __forceinline__ float tanh_fast(float x) {
  // tanh(x) = 1 - 2/(1 + e^{2x});  e^{2x} = exp2(x * 2*log2(e))
  float e = __builtin_amdgcn_exp2f(x * 2.885390081777927f);
  return 1.f - 2.f * __builtin_amdgcn_rcpf(1.f + e);
}

// ---------------------------------------------------------------------------
// Prep: (a) weights -> bf16 MFMA B-fragment order in ws, (b) analytic log_probs
// Fragment layout for mfma_f32_16x16x32_bf16 B operand:
//   lane l holds B[k][col], col = nt*16 + (l&15), k = kt*32 + 8*(l>>4) + j, j=0..7
// ---------------------------------------------------------------------------
__global__ void prep_kernel(const float* __restrict__ W1, const float* __restrict__ b1,
                            const float* __restrict__ W2, const float* __restrict__ W3,
                            const float* __restrict__ W4, const float* __restrict__ x0,
                            const int* __restrict__ jac, float* __restrict__ out,
                            ushort_t* __restrict__ ws) {
  int bid = blockIdx.x;
  int tid = threadIdx.x;
  if (bid < FRAG_BLOCKS) {
    int e = bid * 256 + tid;           // 0 .. 151551
    float val = 0.f;
    if (e < 16384) {                   // W1 (61x256), pad K->64, row61 = b1 (bias fold)
      int kt = e >> 13; int r = e & 8191;
      int nt = r >> 9, l = (r >> 3) & 63, j = r & 7;
      int k = kt * 32 + ((l >> 4) << 3) + j;
      int col = nt * 16 + (l & 15);
      val = (k < 61) ? W1[k * 256 + col] : ((k == 61) ? b1[col] : 0.f);
    } else if (e < 81920) {            // W2 (256x256)
      int e2 = e - 16384;
      int kt = e2 >> 13; int r = e2 & 8191;
      int nt = r >> 9, l = (r >> 3) & 63, j = r & 7;
      int k = kt * 32 + ((l >> 4) << 3) + j;
      int col = nt * 16 + (l & 15);
      val = W2[k * 256 + col];
    } else if (e < 147456) {           // W3 (256x256)
      int e2 = e - 81920;
      int kt = e2 >> 13; int r = e2 & 8191;
      int nt = r >> 9, l = (r >> 3) & 63, j = r & 7;
      int k = kt * 32 + ((l >> 4) << 3) + j;
      int col = nt * 16 + (l & 15);
      val = W3[k * 256 + col];
    } else {                           // W4 (256x12), pad N->16
      int e2 = e - 147456;
      int kt = e2 >> 9; int r = e2 & 511;
      int l = (r >> 3) & 63, j = r & 7;
      int k = kt * 32 + ((l >> 4) << 3) + j;
      int col = l & 15;
      val = (col < 12) ? W4[k * 12 + col] : 0.f;
    }
    ws[e] = f2bf(val);
  } else {
    int s = (bid - FRAG_BLOCKS) * 256 + tid;   // 0..2047
    float acc = 0.f;
    #pragma unroll 4
    for (int j = 0; j < XDIM; ++j) { float v = x0[s * XDIM + j]; acc += v * v; }
    // -0.5*d*ln(2pi) = -22.054524796912143 ; -logabsdet = -240*ln(0.95) = +12.310390653012128
    float C = (jac[0] != 0) ? -9.744134143900015f : -22.054524796912143f;
    out[NB * XDIM + s] = -0.5f * acc + C;
  }
}

// ---------------------------------------------------------------------------
// Main: persistent Heun integrator. 128 blocks x 512 threads (8 waves),
// 16 samples/block. W2 fragment-resident in LDS; W1/W3/W4 slices in registers.
// ---------------------------------------------------------------------------
__global__ __launch_bounds__(512, 2) void flow_main(
    const float* __restrict__ obs, const float* __restrict__ x0,
    const float* __restrict__ b2g, const float* __restrict__ b3g,
    const float* __restrict__ b4g, const ushort_t* __restrict__ ws,
    float* __restrict__ out) {
  extern __shared__ char lds[];
  const int tid  = threadIdx.x;
  const int lane = tid & 63;
  const int wv   = tid >> 6;        // wave 0..7, owns hidden cols [wv*32, wv*32+32)
  const int g    = lane >> 4;       // K-group 0..3
  const int ar   = lane & 15;       // A row / C-D col within tile
  const int row0 = blockIdx.x * 16; // first sample of this block

  // --- init phase A: zero AIN ---
  ((unsigned*)(lds + LDS_AIN))[tid] = 0u;   // 512 dwords = 2048 B

  // --- copy W2 fragments to LDS (131072 B) ---
  {
    const i32x4* __restrict__ src = (const i32x4*)(ws + W2U);
    i32x4* dst = (i32x4*)(lds + LDS_W2);
    #pragma unroll
    for (int it = 0; it < 16; ++it) dst[it * 512 + tid] = src[it * 512 + tid];
  }
  __syncthreads();

  // --- init phase B: obs, bias-one, z/y seed into AIN (swizzled scalar writes) ---
  for (int idx = tid; idx < 16 * OBS_D; idx += 512) {
    int r = idx / OBS_D, o = idx - r * OBS_D;
    int k = 12 + o;
    float v = obs[(row0 + r) * OBS_D + o];
    int byt = (k * 2) ^ ((r & 7) << 4);
    *(ushort_t*)(lds + LDS_AIN + r * 128 + byt) = f2bf(v);
  }
  if (tid < 16) {  // k=61 -> 1.0 (bias row); k=60 (t) stays 0 for step 0
    int byt = (61 * 2) ^ ((tid & 7) << 4);
    *(ushort_t*)(lds + LDS_AIN + tid * 128 + byt) = (ushort_t)0x3F80;
  }
  if (tid < 192) {
    int r = tid / 12, d = tid - r * 12;
    float zv = x0[(row0 + r) * XDIM + d];
    float yv = x0[(row0 + r) * XDIM + 12 + d];
    ((float*)(lds + LDS_Z))[r * 16 + d] = zv;
    ((float*)(lds + LDS_Y))[r * 16 + d] = yv;
    int byt = (d * 2) ^ ((r & 7) << 4);
    *(ushort_t*)(lds + LDS_AIN + r * 128 + byt) = f2bf(yv);  // MLP#1 of step 0 takes y
  }

  // --- resident weight fragments (registers) ---
  s16x8 w1r[2][2], w3r[8][2], w4r;
  #pragma unroll
  for (int kt = 0; kt < 2; ++kt)
    #pragma unroll
    for (int n = 0; n < 2; ++n)
      w1r[kt][n] = *(const s16x8*)(ws + W1U + (((kt * 16) + (2 * wv + n)) * 64 + lane) * 8);
  #pragma unroll
  for (int kt = 0; kt < 8; ++kt)
    #pragma unroll
    for (int n = 0; n < 2; ++n)
      w3r[kt][n] = *(const s16x8*)(ws + W3U + (((kt * 16) + (2 * wv + n)) * 64 + lane) * 8);
  w4r = *(const s16x8*)(ws + W4U + (wv * 64 + lane) * 8);

  float b2r[2], b3r[2];
  #pragma unroll
  for (int n = 0; n < 2; ++n) {
    b2r[n] = b2g[(2 * wv + n) * 16 + ar];
    b3r[n] = b3g[(2 * wv + n) * 16 + ar];
  }
  float b4v = (ar < 12) ? b4g[ar] : 0.f;   // for reduce threads (tid<256: tid&15 == ar)

  __syncthreads();

  const f32x4 z4 = {0.f, 0.f, 0.f, 0.f};

  for (int i = 0; i < NSTEPS; ++i) {
    #pragma unroll
    for (int ev = 0; ev < 2; ++ev) {
      // ---- L1: u1 = [act|obs|t|1] @ W1f  (K=64, b1 folded) ----
      f32x4 acc0 = z4, acc1 = z4;
      #pragma unroll
      for (int kt = 0; kt < 2; ++kt) {
        int off = kt * 64 + g * 16;
        s16x8 a = *(const s16x8*)(lds + LDS_AIN + ar * 128 + (off ^ ((ar & 7) << 4)));
        acc0 = __builtin_amdgcn_mfma_f32_16x16x32_bf16(a, w1r[kt][0], acc0, 0, 0, 0);
        acc1 = __builtin_amdgcn_mfma_f32_16x16x32_bf16(a, w1r[kt][1], acc1, 0, 0, 0);
      }
      #pragma unroll
      for (int n = 0; n < 2; ++n) {
        f32x4 acc = n ? acc1 : acc0;
        int colg = (2 * wv + n) * 16 + ar;
        #pragma unroll
        for (int r = 0; r < 4; ++r) {
          int rw = g * 4 + r;
          float h = tanh_fast(acc[r]);
          int byt = (colg * 2) ^ ((rw & 7) << 4);
          *(ushort_t*)(lds + LDS_BUFA + rw * 512 + byt) = f2bf(h);
        }
      }
      __syncthreads();

      // ---- L2: h1 @ W2 (LDS-resident fragments) ----
      acc0 = z4; acc1 = z4;
      #pragma unroll
      for (int kt = 0; kt < 8; ++kt) {
        int off = kt * 64 + g * 16;
        s16x8 a = *(const s16x8*)(lds + LDS_BUFA + ar * 512 + (off ^ ((ar & 7) << 4)));
        s16x8 bb0 = *(const s16x8*)(lds + LDS_W2 + (((kt * 16) + (2 * wv)) * 64 + lane) * 16);
        s16x8 bb1 = *(const s16x8*)(lds + LDS_W2 + (((kt * 16) + (2 * wv + 1)) * 64 + lane) * 16);
        acc0 = __builtin_amdgcn_mfma_f32_16x16x32_bf16(a, bb0, acc0, 0, 0, 0);
        acc1 = __builtin_amdgcn_mfma_f32_16x16x32_bf16(a, bb1, acc1, 0, 0, 0);
      }
      #pragma unroll
      for (int n = 0; n < 2; ++n) {
        f32x4 acc = n ? acc1 : acc0;
        int colg = (2 * wv + n) * 16 + ar;
        #pragma unroll
        for (int r = 0; r < 4; ++r) {
          int rw = g * 4 + r;
          float h = tanh_fast(acc[r] + b2r[n]);
          int byt = (colg * 2) ^ ((rw & 7) << 4);
          *(ushort_t*)(lds + LDS_BUFB + rw * 512 + byt) = f2bf(h);
        }
      }
      __syncthreads();

      // ---- L3: h2 @ W3 (register-resident fragments) ----
      acc0 = z4; acc1 = z4;
      #pragma unroll
      for (int kt = 0; kt < 8; ++kt) {
        int off = kt * 64 + g * 16;
        s16x8 a = *(const s16x8*)(lds + LDS_BUFB + ar * 512 + (off ^ ((ar & 7) << 4)));
        acc0 = __builtin_amdgcn_mfma_f32_16x16x32_bf16(a, w3r[kt][0], acc0, 0, 0, 0);
        acc1 = __builtin_amdgcn_mfma_f32_16x16x32_bf16(a, w3r[kt][1], acc1, 0, 0, 0);
      }
      #pragma unroll
      for (int n = 0; n < 2; ++n) {
        f32x4 acc = n ? acc1 : acc0;
        int colg = (2 * wv + n) * 16 + ar;
        #pragma unroll
        for (int r = 0; r < 4; ++r) {
          int rw = g * 4 + r;
          float h = tanh_fast(acc[r] + b3r[n]);
          int byt = (colg * 2) ^ ((rw & 7) << 4);
          *(ushort_t*)(lds + LDS_BUFA + rw * 512 + byt) = f2bf(h);
        }
      }
      __syncthreads();

      // ---- L4: h3 @ W4, K split across 8 waves (ktile = wv), partials -> BUFB ----
      {
        int off = wv * 64 + g * 16;
        s16x8 a = *(const s16x8*)(lds + LDS_BUFA + ar * 512 + (off ^ ((ar & 7) << 4)));
        f32x4 p = __builtin_amdgcn_mfma_f32_16x16x32_bf16(a, w4r, z4, 0, 0, 0);
        #pragma unroll
        for (int r = 0; r < 4; ++r) {
          int rw = g * 4 + r;
          *(float*)(lds + LDS_BUFB + wv * 1024 + (rw * 16 + ar) * 4) = p[r];
        }
      }
      __syncthreads();

      // ---- reduce + Heun update (threads 0..255: row = tid>>4, col = tid&15) ----
      if (tid < 256) {
        float s = b4v;
        #pragma unroll
        for (int w = 0; w < 8; ++w) s += *(const float*)(lds + LDS_BUFB + w * 1024 + tid * 4);
        int r = tid >> 4, c = tid & 15;
        if (c < 12) {
          int byt = (c * 2) ^ ((r & 7) << 4);
          if (ev == 0) {
            float zi = ((float*)(lds + LDS_Z))[tid] + DT * s;
            ((float*)(lds + LDS_ZI))[tid] = zi;
            *(ushort_t*)(lds + LDS_AIN + r * 128 + byt) = f2bf(zi);   // MLP#2 input
          } else {
            float yi = ((float*)(lds + LDS_Y))[tid] + DT * s;
            float zi = ((float*)(lds + LDS_ZI))[tid];
            float zn = PP * zi + (1.f - PP) * yi;
            float yn = PP * yi + (1.f - PP) * zn;
            ((float*)(lds + LDS_Z))[tid] = zn;
            ((float*)(lds + LDS_Y))[tid] = yn;
            *(ushort_t*)(lds + LDS_AIN + r * 128 + byt) = f2bf(yn);   // next step MLP#1 input
          }
        }
        if (ev == 1 && c == 15) {  // stage t for next step
          float tn = (float)(i + 1) * DT;
          int byt = (60 * 2) ^ ((r & 7) << 4);
          *(ushort_t*)(lds + LDS_AIN + r * 128 + byt) = f2bf(tn);
        }
      }
      __syncthreads();
    }
  }

  // ---- output: action_aug = [z | y] ----
  if (tid < 256) {
    int r = tid >> 4, c = tid & 15;
    if (c < 12) {
      out[(row0 + r) * XDIM + c]      = ((float*)(lds + LDS_Z))[tid];
      out[(row0 + r) * XDIM + 12 + c] = ((float*)(lds + LDS_Y))[tid];
    }
  }
}

extern "C" void kernel_launch(void* const* d_in, const int* in_sizes, int n_in,
                              void* d_out, int out_size, void* d_ws, size_t ws_size,
                              hipStream_t stream) {
  const float* obs = (const float*)d_in[0];
  const float* x0  = (const float*)d_in[1];
  const float* W1  = (const float*)d_in[2];
  const float* b1  = (const float*)d_in[3];
  const float* W2  = (const float*)d_in[4];
  const float* b2  = (const float*)d_in[5];
  const float* W3  = (const float*)d_in[6];
  const float* b3  = (const float*)d_in[7];
  const float* W4  = (const float*)d_in[8];
  const float* b4  = (const float*)d_in[9];
  const int*   jac = (const int*)d_in[10];
  float* out = (float*)d_out;
  ushort_t* ws = (ushort_t*)d_ws;

  hipFuncSetAttribute((const void*)flow_main,
                      hipFuncAttributeMaxDynamicSharedMemorySize, LDS_TOTAL);

  prep_kernel<<<FRAG_BLOCKS + LP_BLOCKS, 256, 0, stream>>>(W1, b1, W2, W3, W4, x0, jac, out, ws);
  flow_main<<<128, 512, LDS_TOTAL, stream>>>(obs, x0, b2, b3, b4, ws, out);
}

// Round 4
// 49.714 us; speedup vs baseline: 1.1374x; 1.1374x over previous
//
#include <hip/hip_runtime.h>
#include <hip/hip_bf16.h>

// Flow_6081673691683: Heun flow (10 steps x 2 MLP evals, H=256) + analytic logdet.
// logabsdet = 240*ln(0.95) exactly (two unit shears + det-P^2 mixing per step).
// R4: all weights register-resident (W2 was the 128KB/eval LDS hog), permuted-K
// packed h-layout (b32 writes, bank-uniform b128 reads), L4 fused into L3
// (wave-local slice, lgkmcnt instead of barrier), z/y/zi in registers.

typedef unsigned short ushort_t;
typedef float f32x4 __attribute__((ext_vector_type(4)));
typedef short s16x8 __attribute__((ext_vector_type(8)));

#define NB      2048
#define OBS_D   48
#define HDIM    256
#define ADIM    12
#define XDIM    24
#define NSTEPS  10
#define DT      0.1f
#define PP      0.95f

// d_ws layout (ushort / bf16 elements)
#define W1U 0        // 2kt * 16nt * 64 * 8 = 16384
#define W2U 16384    // 8kt * 16nt * 64 * 8 = 65536
#define W3U 81920    // 65536
#define W4U 147456   // 8kt * 64 * 8 = 4096
#define N_FRAG 151552
#define FRAG_BLOCKS 592   // 592*256 == 151552
#define LP_BLOCKS 8       // 8*256 == 2048

// LDS layout (bytes). h-buffers: 16 rows x (8 segs x 64B), row stride 576,
// segment base shifted +64B for rows with (row>>2)&1 (bank spread).
// Within a segment, dword d = cols (kt*32+d [lo], kt*32+16+d [hi]).
#define LDS_BUFA 0        // 9216
#define LDS_BUFB 9216     // 9216
#define LDS_AIN  18432    // 3072 (16 rows x 192B: 2 segs + spare, stride-192 spreads banks)
#define LDS_PART 21504    // 10240 (8 waves x [16 rows x 80B])
#define LDS_TOTAL 31744

__device__ __forceinline__ ushort_t f2bf(float f) {
  unsigned u = __builtin_bit_cast(unsigned, f);
  u += 0x7fffu + ((u >> 16) & 1u);          // RNE
  return (ushort_t)(u >> 16);
}

__device__ __forceinline__ float tanh_fast(float x) {
  float e = __builtin_amdgcn_exp2f(x * 2.885390081777927f);
  return 1.f - 2.f * __builtin_amdgcn_rcpf(1.f + e);
}

// AIN byte offset for (row, col) under the packed-pair layout (stride 192)
__device__ __forceinline__ int ain_byte(int r, int c) {
  return r * 192 + ((c >> 5) << 6) + ((c & 15) << 2) + (((c >> 4) & 1) << 1);
}

// ---------------------------------------------------------------------------
// Prep: weights -> bf16 MFMA B-fragment order (with permuted K) + log_probs.
// Fragment (kt, nt, lane l, j) holds W[k_eff][nt*16 + (l&15)] with
//   k_eff = kt*32 + 4*(l>>4) + (j>>1) + 16*(j&1)
// matching the packed h storage (dword d of a segment = cols {d, d+16}).
// ---------------------------------------------------------------------------
__global__ void prep_kernel(const float* __restrict__ W1, const float* __restrict__ b1,
                            const float* __restrict__ W2, const float* __restrict__ W3,
                            const float* __restrict__ W4, const float* __restrict__ x0,
                            const int* __restrict__ jac, float* __restrict__ out,
                            ushort_t* __restrict__ ws) {
  int bid = blockIdx.x;
  int tid = threadIdx.x;
  if (bid < FRAG_BLOCKS) {
    int e = bid * 256 + tid;           // 0 .. 151551
    float val = 0.f;
    if (e < 16384) {                   // W1 (61x256 + b1 row 61), K padded to 64
      int kt = e >> 13; int r = e & 8191;
      int nt = r >> 9, l = (r >> 3) & 63, j = r & 7;
      int k = kt * 32 + ((l >> 4) << 2) + (j >> 1) + ((j & 1) << 4);
      int col = nt * 16 + (l & 15);
      val = (k < 61) ? W1[k * 256 + col] : ((k == 61) ? b1[col] : 0.f);
    } else if (e < 81920) {            // W2 (256x256)
      int e2 = e - 16384;
      int kt = e2 >> 13; int r = e2 & 8191;
      int nt = r >> 9, l = (r >> 3) & 63, j = r & 7;
      int k = kt * 32 + ((l >> 4) << 2) + (j >> 1) + ((j & 1) << 4);
      int col = nt * 16 + (l & 15);
      val = W2[k * 256 + col];
    } else if (e < 147456) {           // W3 (256x256)
      int e2 = e - 81920;
      int kt = e2 >> 13; int r = e2 & 8191;
      int nt = r >> 9, l = (r >> 3) & 63, j = r & 7;
      int k = kt * 32 + ((l >> 4) << 2) + (j >> 1) + ((j & 1) << 4);
      int col = nt * 16 + (l & 15);
      val = W3[k * 256 + col];
    } else {                           // W4 (256x12), N padded to 16
      int e2 = e - 147456;
      int kt = e2 >> 9; int r = e2 & 511;
      int l = (r >> 3) & 63, j = r & 7;
      int k = kt * 32 + ((l >> 4) << 2) + (j >> 1) + ((j & 1) << 4);
      int col = l & 15;
      val = (col < 12) ? W4[k * 12 + col] : 0.f;
    }
    ws[e] = f2bf(val);
  } else {
    int s = (bid - FRAG_BLOCKS) * 256 + tid;   // 0..2047
    float acc = 0.f;
    #pragma unroll 4
    for (int j = 0; j < XDIM; ++j) { float v = x0[s * XDIM + j]; acc += v * v; }
    // -0.5*d*ln(2pi) = -22.054524796912143 ; -240*ln(0.95) = +12.310390653012128
    float C = (jac[0] != 0) ? -9.744134143900015f : -22.054524796912143f;
    out[NB * XDIM + s] = -0.5f * acc + C;
  }
}

// ---------------------------------------------------------------------------
// Main: 128 blocks x 512 threads (8 waves), 16 samples/block.
// ALL weights register-resident (W1 16 + W2 64 + W3 64 + W4 4 = 148 VGPR).
// ---------------------------------------------------------------------------
__global__ __launch_bounds__(512, 2) void flow_main(
    const float* __restrict__ obs, const float* __restrict__ x0,
    const float* __restrict__ b2g, const float* __restrict__ b3g,
    const float* __restrict__ b4g, const ushort_t* __restrict__ ws,
    float* __restrict__ out) {
  __shared__ char lds[LDS_TOTAL];
  const int tid  = threadIdx.x;
  const int lane = tid & 63;
  const int wv   = tid >> 6;        // wave 0..7, owns hidden cols [wv*32, wv*32+32)
  const int g    = lane >> 4;       // K-group 0..3
  const int ar   = lane & 15;       // A row / C-D col within tile
  const int row0 = blockIdx.x * 16;

  // per-thread LDS address bases
  const int aA = LDS_AIN + ar * 192 + g * 16;                 // + kt*64 (A-frag read, AIN)
  const int hA = ar * 576 + (((ar >> 2) & 1) << 6) + g * 16;  // + buf + kt*64 (A-frag read, h)
  const int hw = (g * 4) * 576 + ((g & 1) << 6) + wv * 64 + ar * 4; // + buf + r*576 (h write)
  const int pw = LDS_PART + wv * 1280 + (g * 4) * 80 + ar * 4;      // + r*80 (partial write)
  const int rs = tid >> 4, cs = tid & 15;                     // reduce-role (tid<256)

  // --- zero AIN (768 dwords), then barrier before partial u16 fills ---
  for (int p = tid; p < 768; p += 512) ((unsigned*)(lds + LDS_AIN))[p] = 0u;
  __syncthreads();

  // --- obs, bias-one, y-seed into AIN ---
  for (int idx = tid; idx < 16 * OBS_D; idx += 512) {
    int r = idx / OBS_D, o = idx - r * OBS_D;
    *(ushort_t*)(lds + LDS_AIN + ain_byte(r, 12 + o)) = f2bf(obs[(row0 + r) * OBS_D + o]);
  }
  if (tid < 16)  // col 61 = 1.0 (bias); col 60 (t) stays 0 for step 0
    *(ushort_t*)(lds + LDS_AIN + tid * 192 + 118) = (ushort_t)0x3F80;

  float zr = 0.f, yr = 0.f, zir = 0.f;
  if (tid < 256 && cs < 12) {
    zr = x0[(row0 + rs) * XDIM + cs];
    yr = x0[(row0 + rs) * XDIM + 12 + cs];
    *(ushort_t*)(lds + LDS_AIN + rs * 192 + cs * 4) = f2bf(yr);  // MLP#1 of step 0 takes y
  }

  // --- register-resident weight fragments ---
  s16x8 w1r[2][2], w2r[8][2], w3r[8][2], w4r;
  #pragma unroll
  for (int kt = 0; kt < 2; ++kt)
    #pragma unroll
    for (int n = 0; n < 2; ++n)
      w1r[kt][n] = *(const s16x8*)(ws + W1U + (((kt * 16) + (2 * wv + n)) * 64 + lane) * 8);
  #pragma unroll
  for (int kt = 0; kt < 8; ++kt)
    #pragma unroll
    for (int n = 0; n < 2; ++n) {
      w2r[kt][n] = *(const s16x8*)(ws + W2U + (((kt * 16) + (2 * wv + n)) * 64 + lane) * 8);
      w3r[kt][n] = *(const s16x8*)(ws + W3U + (((kt * 16) + (2 * wv + n)) * 64 + lane) * 8);
    }
  w4r = *(const s16x8*)(ws + W4U + (wv * 64 + lane) * 8);

  float b2r[2], b3r[2];
  #pragma unroll
  for (int n = 0; n < 2; ++n) {
    b2r[n] = b2g[(2 * wv + n) * 16 + ar];
    b3r[n] = b3g[(2 * wv + n) * 16 + ar];
  }
  const float b4v = (cs < 12) ? b4g[cs] : 0.f;

  __syncthreads();

  const f32x4 z4 = {0.f, 0.f, 0.f, 0.f};

  for (int i = 0; i < NSTEPS; ++i) {
    #pragma unroll
    for (int ev = 0; ev < 2; ++ev) {
      // ---- L1: [act|obs|t|1] @ W1 (K=64, b1 folded) ----
      f32x4 acc0 = z4, acc1 = z4;
      #pragma unroll
      for (int kt = 0; kt < 2; ++kt) {
        s16x8 a = *(const s16x8*)(lds + aA + kt * 64);
        acc0 = __builtin_amdgcn_mfma_f32_16x16x32_bf16(a, w1r[kt][0], acc0, 0, 0, 0);
        acc1 = __builtin_amdgcn_mfma_f32_16x16x32_bf16(a, w1r[kt][1], acc1, 0, 0, 0);
      }
      #pragma unroll
      for (int r = 0; r < 4; ++r) {
        unsigned p = (unsigned)f2bf(tanh_fast(acc0[r]))
                   | ((unsigned)f2bf(tanh_fast(acc1[r])) << 16);
        *(unsigned*)(lds + LDS_BUFA + hw + r * 576) = p;
      }
      __syncthreads();

      // ---- L2: h1 @ W2 (register fragments) ----
      acc0 = z4; acc1 = z4;
      #pragma unroll
      for (int kt = 0; kt < 8; ++kt) {
        s16x8 a = *(const s16x8*)(lds + LDS_BUFA + hA + kt * 64);
        acc0 = __builtin_amdgcn_mfma_f32_16x16x32_bf16(a, w2r[kt][0], acc0, 0, 0, 0);
        acc1 = __builtin_amdgcn_mfma_f32_16x16x32_bf16(a, w2r[kt][1], acc1, 0, 0, 0);
      }
      #pragma unroll
      for (int r = 0; r < 4; ++r) {
        unsigned p = (unsigned)f2bf(tanh_fast(acc0[r] + b2r[0]))
                   | ((unsigned)f2bf(tanh_fast(acc1[r] + b2r[1])) << 16);
        *(unsigned*)(lds + LDS_BUFB + hw + r * 576) = p;
      }
      __syncthreads();

      // ---- L3: h2 @ W3 ----
      acc0 = z4; acc1 = z4;
      #pragma unroll
      for (int kt = 0; kt < 8; ++kt) {
        s16x8 a = *(const s16x8*)(lds + LDS_BUFB + hA + kt * 64);
        acc0 = __builtin_amdgcn_mfma_f32_16x16x32_bf16(a, w3r[kt][0], acc0, 0, 0, 0);
        acc1 = __builtin_amdgcn_mfma_f32_16x16x32_bf16(a, w3r[kt][1], acc1, 0, 0, 0);
      }
      #pragma unroll
      for (int r = 0; r < 4; ++r) {
        unsigned p = (unsigned)f2bf(tanh_fast(acc0[r] + b3r[0]))
                   | ((unsigned)f2bf(tanh_fast(acc1[r] + b3r[1])) << 16);
        *(unsigned*)(lds + LDS_BUFA + hw + r * 576) = p;
      }

      // ---- L4 fused (NO barrier): wave wv's K-slice == the h3 cols it just wrote ----
      asm volatile("s_waitcnt lgkmcnt(0)" ::: "memory");
      __builtin_amdgcn_sched_barrier(0);
      {
        s16x8 a = *(const s16x8*)(lds + LDS_BUFA + hA + wv * 64);
        f32x4 p4 = __builtin_amdgcn_mfma_f32_16x16x32_bf16(a, w4r, z4, 0, 0, 0);
        #pragma unroll
        for (int r = 0; r < 4; ++r)
          *(float*)(lds + pw + r * 80) = p4[r];
      }
      __syncthreads();

      // ---- reduce + Heun update (threads 0..255) ----
      if (tid < 256) {
        float s = b4v;
        #pragma unroll
        for (int w = 0; w < 8; ++w)
          s += *(const float*)(lds + LDS_PART + w * 1280 + rs * 80 + cs * 4);
        if (cs < 12) {
          if (ev == 0) {
            zir = zr + DT * s;
            *(ushort_t*)(lds + LDS_AIN + rs * 192 + cs * 4) = f2bf(zir);  // MLP#2 input
          } else {
            float yi = yr + DT * s;
            zr = PP * zir + (1.f - PP) * yi;
            yr = PP * yi + (1.f - PP) * zr;
            *(ushort_t*)(lds + LDS_AIN + rs * 192 + cs * 4) = f2bf(yr);   // next MLP#1 input
          }
        }
        if (ev == 1 && cs == 15)  // stage t = (i+1)/10 for next step (col 60)
          *(ushort_t*)(lds + LDS_AIN + rs * 192 + 114) = f2bf((float)(i + 1) * DT);
      }
      __syncthreads();
    }
  }

  // ---- output: action_aug = [z | y] from registers ----
  if (tid < 256 && cs < 12) {
    out[(row0 + rs) * XDIM + cs]      = zr;
    out[(row0 + rs) * XDIM + 12 + cs] = yr;
  }
}

extern "C" void kernel_launch(void* const* d_in, const int* in_sizes, int n_in,
                              void* d_out, int out_size, void* d_ws, size_t ws_size,
                              hipStream_t stream) {
  const float* obs = (const float*)d_in[0];
  const float* x0  = (const float*)d_in[1];
  const float* W1  = (const float*)d_in[2];
  const float* b1  = (const float*)d_in[3];
  const float* W2  = (const float*)d_in[4];
  const float* b2  = (const float*)d_in[5];
  const float* W3  = (const float*)d_in[6];
  const float* b3  = (const float*)d_in[7];
  const float* W4  = (const float*)d_in[8];
  const float* b4  = (const float*)d_in[9];
  const int*   jac = (const int*)d_in[10];
  float* out = (float*)d_out;
  ushort_t* ws = (ushort_t*)d_ws;

  prep_kernel<<<FRAG_BLOCKS + LP_BLOCKS, 256, 0, stream>>>(W1, b1, W2, W3, W4, x0, jac, out, ws);
  flow_main<<<128, 512, 0, stream>>>(obs, x0, b2, b3, b4, ws, out);
}